// Round 5
// baseline (56.972 us; speedup 1.0000x reference)
//
#include <hip/hip_runtime.h>
#include <hip/hip_cooperative_groups.h>

namespace cg = cooperative_groups;

#define FEAT 2048
#define CH 16            // output rows per chunk
#define COLSPLIT 4
#define THREADS 128      // 128 threads * 4 floats = 512 = FEAT/COLSPLIT

// total = sum_r sum_{delta=1..4} W(r,delta) * g(r, r+delta),
// g(r,s) = sum_feat relu(x_r - x_s), W(r,delta) = sum_{i=0}^{4-delta} cnt[r-i],
// cnt[v] = multiplicity of base value v = batch*distort (batch<64, distort<24).
struct Tables {
    int nchunk;
    short r0[1456];
    float W[1472][4];
};

constexpr Tables make_tables() {
    Tables t{};
    int cnt[1450] = {};
    for (int b = 0; b < 64; ++b)
        for (int d = 0; d < 24; ++d)
            cnt[b * d]++;
    for (int r = 0; r < 1472; ++r)
        for (int dl = 1; dl <= 4; ++dl) {
            int s = 0;
            for (int i = 0; i <= 4 - dl; ++i) {
                int v = r - i;
                if (v >= 0 && v < 1450) s += cnt[v];
            }
            t.W[r][dl - 1] = (float)s;
        }
    t.nchunk = 0;
    int r = 0;
    while (r < 1453) {
        bool act = false;
        for (int i = 0; i <= 3; ++i) {
            int v = r - i;
            if (v >= 0 && v < 1450 && cnt[v] > 0) act = true;
        }
        if (act) { t.r0[t.nchunk++] = (short)r; r += CH; }
        else ++r;
    }
    return t;
}

constexpr Tables TBL = make_tables();
constexpr int NCHUNK = TBL.nchunk;
constexpr int NPART  = NCHUNK * COLSPLIT;

__constant__ Tables d_tbl = make_tables();

__global__ __launch_bounds__(THREADS) void hinge_coop(const float* __restrict__ in,
                                                      float* __restrict__ partial,
                                                      float* __restrict__ out) {
    const int chunk = blockIdx.x / COLSPLIT;
    const int chalf = blockIdx.x % COLSPLIT;
    const int r0    = d_tbl.r0[chunk];
    const float* p  = in + (long)r0 * FEAT + chalf * (FEAT / COLSPLIT) + threadIdx.x * 4;

    float4 x[5];
    #pragma unroll
    for (int l = 0; l < 4; ++l)
        x[l] = *(const float4*)(p + l * FEAT);

    float acc0 = 0.f, acc1 = 0.f;
    #pragma unroll
    for (int k = 0; k < CH; ++k) {
        x[4] = *(const float4*)(p + (k + 4) * FEAT);
        #pragma unroll
        for (int dl = 1; dl <= 4; ++dl) {
            const float w = d_tbl.W[r0 + k][dl - 1];
            float s = fmaxf(x[0].x - x[dl].x, 0.f)
                    + fmaxf(x[0].y - x[dl].y, 0.f)
                    + fmaxf(x[0].z - x[dl].z, 0.f)
                    + fmaxf(x[0].w - x[dl].w, 0.f);
            if (dl & 1) acc0 = fmaf(w, s, acc0);
            else        acc1 = fmaf(w, s, acc1);
        }
        #pragma unroll
        for (int l = 0; l < 4; ++l) x[l] = x[l + 1];
    }

    float acc = acc0 + acc1;
    #pragma unroll
    for (int off = 32; off > 0; off >>= 1)
        acc += __shfl_down(acc, off, 64);

    __shared__ float ws2[2];
    const int lane = threadIdx.x & 63, wave = threadIdx.x >> 6;
    if (lane == 0) ws2[wave] = acc;
    __syncthreads();
    if (threadIdx.x == 0) {
        partial[blockIdx.x] = ws2[0] + ws2[1];
        __threadfence();   // make partial visible device-wide before grid sync
    }

    cg::this_grid().sync();

    if (blockIdx.x == 0) {
        float a = 0.f;
        for (int i = threadIdx.x; i < NPART; i += THREADS) a += partial[i];
        #pragma unroll
        for (int off = 32; off > 0; off >>= 1)
            a += __shfl_down(a, off, 64);
        if (lane == 0) ws2[wave] = a;
        __syncthreads();
        if (threadIdx.x == 0) out[0] = ws2[0] + ws2[1];
    }
}

extern "C" void kernel_launch(void* const* d_in, const int* in_sizes, int n_in,
                              void* d_out, int out_size, void* d_ws, size_t ws_size,
                              hipStream_t stream) {
    const float* in = (const float*)d_in[0];
    float* out      = (float*)d_out;
    float* partial  = (float*)d_ws;   // NPART floats

    void* args[] = { (void*)&in, (void*)&partial, (void*)&out };
    hipLaunchCooperativeKernel((const void*)hinge_coop,
                               dim3(NPART), dim3(THREADS), args, 0, stream);
}

// Round 6
// 11.053 us; speedup vs baseline: 5.1546x; 5.1546x over previous
//
#include <hip/hip_runtime.h>

#define FEAT 2048
#define CH 8             // output rows per chunk
#define COLSPLIT 8
#define THREADS 64       // 64 threads * 4 floats = 256 = FEAT/COLSPLIT
#define NROWS_LD (CH + 4)

// total = sum_r sum_{delta=1..4} W(r,delta) * g(r, r+delta),
// g(r,s) = sum_feat relu(x_r - x_s), W(r,delta) = sum_{i=0}^{4-delta} cnt[r-i],
// cnt[v] = multiplicity of base value v = batch*distort (batch<64, distort<24).
struct Tables {
    int nchunk;
    short r0[1456];
    float W[1472][4];
};

constexpr Tables make_tables() {
    Tables t{};
    int cnt[1450] = {};
    for (int b = 0; b < 64; ++b)
        for (int d = 0; d < 24; ++d)
            cnt[b * d]++;
    for (int r = 0; r < 1472; ++r)
        for (int dl = 1; dl <= 4; ++dl) {
            int s = 0;
            for (int i = 0; i <= 4 - dl; ++i) {
                int v = r - i;
                if (v >= 0 && v < 1450) s += cnt[v];
            }
            t.W[r][dl - 1] = (float)s;
        }
    t.nchunk = 0;
    int r = 0;
    while (r < 1453) {
        bool act = false;
        for (int i = 0; i <= 3; ++i) {
            int v = r - i;
            if (v >= 0 && v < 1450 && cnt[v] > 0) act = true;
        }
        if (act) { t.r0[t.nchunk++] = (short)r; r += CH; }
        else ++r;
    }
    return t;
}

constexpr Tables TBL = make_tables();
constexpr int NCHUNK = TBL.nchunk;
constexpr int NPART  = NCHUNK * COLSPLIT;

__constant__ Tables d_tbl = make_tables();

__global__ __launch_bounds__(THREADS) void hinge_rows(const float* __restrict__ in,
                                                      float* __restrict__ partial) {
    const int chunk = blockIdx.x >> 3;        // / COLSPLIT
    const int cpart = blockIdx.x & 7;         // % COLSPLIT
    const int r0    = d_tbl.r0[chunk];
    const float* p  = in + (long)r0 * FEAT + cpart * (FEAT / COLSPLIT) + threadIdx.x * 4;

    // All loads upfront — independent, one latency burst.
    float4 x[NROWS_LD];
    #pragma unroll
    for (int l = 0; l < NROWS_LD; ++l)
        x[l] = *(const float4*)(p + l * FEAT);

    float acc0 = 0.f, acc1 = 0.f;
    #pragma unroll
    for (int k = 0; k < CH; ++k) {
        #pragma unroll
        for (int dl = 1; dl <= 4; ++dl) {
            const float w = d_tbl.W[r0 + k][dl - 1];
            float s = fmaxf(x[k].x - x[k + dl].x, 0.f)
                    + fmaxf(x[k].y - x[k + dl].y, 0.f)
                    + fmaxf(x[k].z - x[k + dl].z, 0.f)
                    + fmaxf(x[k].w - x[k + dl].w, 0.f);
            if (dl & 1) acc0 = fmaf(w, s, acc0);
            else        acc1 = fmaf(w, s, acc1);
        }
    }

    float acc = acc0 + acc1;
    #pragma unroll
    for (int off = 32; off > 0; off >>= 1)
        acc += __shfl_down(acc, off, 64);

    if (threadIdx.x == 0) partial[blockIdx.x] = acc;
}

__global__ __launch_bounds__(256) void reduce_final(const float* __restrict__ partial,
                                                    float* __restrict__ out) {
    const int t = threadIdx.x;
    constexpr int NV4 = NPART / 4;            // NPART divisible by 4 (COLSPLIT=8)
    float acc = 0.f;
    for (int i = t; i < NV4; i += 256) {
        float4 v = ((const float4*)partial)[i];
        acc += (v.x + v.y) + (v.z + v.w);
    }

    #pragma unroll
    for (int off = 32; off > 0; off >>= 1)
        acc += __shfl_down(acc, off, 64);

    __shared__ float ws[4];
    const int lane = t & 63, wave = t >> 6;
    if (lane == 0) ws[wave] = acc;
    __syncthreads();
    if (t == 0) out[0] = (ws[0] + ws[1]) + (ws[2] + ws[3]);
}

extern "C" void kernel_launch(void* const* d_in, const int* in_sizes, int n_in,
                              void* d_out, int out_size, void* d_ws, size_t ws_size,
                              hipStream_t stream) {
    const float* in  = (const float*)d_in[0];
    float* out       = (float*)d_out;
    float* partial   = (float*)d_ws;   // NPART floats (< 6 KiB)

    hinge_rows<<<NPART, THREADS, 0, stream>>>(in, partial);
    reduce_final<<<1, 256, 0, stream>>>(partial, out);
}

// Round 7
// 10.953 us; speedup vs baseline: 5.2015x; 1.0091x over previous
//
#include <hip/hip_runtime.h>

#define FEAT 2048
#define CH 8             // output rows per chunk
#define COLSPLIT 8
#define THREADS 64       // 64 threads * 4 floats = 256 = FEAT/COLSPLIT
#define NROWS_LD (CH + 4)

// total = sum_r sum_{delta=1..4} W(r,delta) * g(r, r+delta),
// g(r,s) = sum_feat relu(x_r - x_s), W(r,delta) = sum_{i=0}^{4-delta} cnt[r-i],
// cnt[v] = multiplicity of base value v = batch*distort (batch<64, distort<24).
struct Tables {
    int nchunk;
    short r0[1456];
    float W[1472][4];
};

constexpr Tables make_tables() {
    Tables t{};
    int cnt[1450] = {};
    for (int b = 0; b < 64; ++b)
        for (int d = 0; d < 24; ++d)
            cnt[b * d]++;
    for (int r = 0; r < 1472; ++r)
        for (int dl = 1; dl <= 4; ++dl) {
            int s = 0;
            for (int i = 0; i <= 4 - dl; ++i) {
                int v = r - i;
                if (v >= 0 && v < 1450) s += cnt[v];
            }
            t.W[r][dl - 1] = (float)s;
        }
    t.nchunk = 0;
    int r = 0;
    while (r < 1453) {
        bool act = false;
        for (int i = 0; i <= 3; ++i) {
            int v = r - i;
            if (v >= 0 && v < 1450 && cnt[v] > 0) act = true;
        }
        if (act) { t.r0[t.nchunk++] = (short)r; r += CH; }
        else ++r;
    }
    return t;
}

constexpr Tables TBL = make_tables();
constexpr int NCHUNK = TBL.nchunk;
constexpr int NPART  = NCHUNK * COLSPLIT;

__constant__ Tables d_tbl = make_tables();

__global__ __launch_bounds__(THREADS) void hinge_rows(const float* __restrict__ in,
                                                      float* __restrict__ partial) {
    const int chunk = blockIdx.x >> 3;        // / COLSPLIT
    const int cpart = blockIdx.x & 7;         // % COLSPLIT
    const int r0    = d_tbl.r0[chunk];
    const float* p  = in + (long)r0 * FEAT + cpart * (FEAT / COLSPLIT) + threadIdx.x * 4;

    // All loads upfront — independent, one latency burst.
    float4 x[NROWS_LD];
    #pragma unroll
    for (int l = 0; l < NROWS_LD; ++l)
        x[l] = *(const float4*)(p + l * FEAT);

    float acc0 = 0.f, acc1 = 0.f;
    #pragma unroll
    for (int k = 0; k < CH; ++k) {
        #pragma unroll
        for (int dl = 1; dl <= 4; ++dl) {
            const float w = d_tbl.W[r0 + k][dl - 1];
            float s = fmaxf(x[k].x - x[k + dl].x, 0.f)
                    + fmaxf(x[k].y - x[k + dl].y, 0.f)
                    + fmaxf(x[k].z - x[k + dl].z, 0.f)
                    + fmaxf(x[k].w - x[k + dl].w, 0.f);
            if (dl & 1) acc0 = fmaf(w, s, acc0);
            else        acc1 = fmaf(w, s, acc1);
        }
    }

    float acc = acc0 + acc1;
    #pragma unroll
    for (int off = 32; off > 0; off >>= 1)
        acc += __shfl_down(acc, off, 64);

    if (threadIdx.x == 0) partial[blockIdx.x] = acc;
}

__global__ __launch_bounds__(256) void reduce_final(const float* __restrict__ partial,
                                                    float* __restrict__ out) {
    const int t = threadIdx.x;
    constexpr int NV4 = NPART / 4;            // NPART divisible by 4 (COLSPLIT=8)
    float acc = 0.f;
    for (int i = t; i < NV4; i += 256) {
        float4 v = ((const float4*)partial)[i];
        acc += (v.x + v.y) + (v.z + v.w);
    }

    #pragma unroll
    for (int off = 32; off > 0; off >>= 1)
        acc += __shfl_down(acc, off, 64);

    __shared__ float ws[4];
    const int lane = t & 63, wave = t >> 6;
    if (lane == 0) ws[wave] = acc;
    __syncthreads();
    if (t == 0) out[0] = (ws[0] + ws[1]) + (ws[2] + ws[3]);
}

extern "C" void kernel_launch(void* const* d_in, const int* in_sizes, int n_in,
                              void* d_out, int out_size, void* d_ws, size_t ws_size,
                              hipStream_t stream) {
    const float* in  = (const float*)d_in[0];
    float* out       = (float*)d_out;
    float* partial   = (float*)d_ws;   // NPART floats (< 6 KiB)

    hinge_rows<<<NPART, THREADS, 0, stream>>>(in, partial);
    reduce_final<<<1, 256, 0, stream>>>(partial, out);
}